// Round 2
// baseline (2228.384 us; speedup 1.0000x reference)
//
#include <hip/hip_runtime.h>

#define NPIX (8 * 1024 * 1024)
#define IN 8
#define HID 16
#define OUTC 3
#define BLK 256
#define PPT 2   // pixels per thread (PPT=4 hit the 256-VGPR cliff -> 11% occupancy)

// Mask may be stored as 1-byte bools (numpy bool_) or widened int32 — detect at
// runtime. Random 0/1 bytes packed into u32 words give values > 1 almost surely;
// int32 storage gives only {0,1}. Reads 2 KB, safe under both layouts (>= 8 MB).
__global__ void detect_mask_kernel(const unsigned int* __restrict__ m,
                                   int* __restrict__ flag) {
    const int t = threadIdx.x;            // 64 lanes, one wave
    unsigned int acc = 0u;
    #pragma unroll
    for (int k = 0; k < 8; ++k) acc |= m[t * 8 + k];
    const unsigned long long any_big = __ballot(acc > 1u);
    if (t == 0) *flag = (any_big != 0ull) ? 1 : 0;  // 1 => byte-mask
}

__global__ void __launch_bounds__(BLK, 4) colormlp_kernel(
    const float* __restrict__ x,
    const void*  __restrict__ mask,
    const float* __restrict__ w0, const float* __restrict__ b0,
    const float* __restrict__ w1, const float* __restrict__ b1,
    const float* __restrict__ w2, const float* __restrict__ b2,
    float* __restrict__ out,
    const int* __restrict__ flag)
{
    // Weights transposed so each output-neuron row is contiguous -> ds_read_b128
    // broadcast (all lanes same address, conflict-free).
    __shared__ __align__(16) float sW0[HID][IN];
    __shared__ __align__(16) float sW1[HID][HID];
    __shared__ __align__(16) float sW2[OUTC][HID];
    __shared__ float sB0[HID];
    __shared__ float sB1[HID];
    __shared__ float sB2[OUTC];
    // Output staging: block covers 512 px * 3 ch = 1536 floats = 6 KB.
    __shared__ __align__(16) float sOut[BLK * PPT * OUTC];

    const int t = threadIdx.x;
    if (t < HID * IN)   { int j = t >> 3, i = t & 7;  sW0[j][i] = w0[i * HID + j]; }
    {                     int j = t >> 4, i = t & 15; sW1[j][i] = w1[i * HID + j]; }
    if (t < OUTC * HID) { int j = t >> 4, i = t & 15; sW2[j][i] = w2[i * OUTC + j]; }
    if (t < HID)  { sB0[t] = b0[t]; sB1[t] = b1[t]; }
    if (t < OUTC) { sB2[t] = b2[t]; }
    __syncthreads();

    const int mflag = *flag;

    const unsigned int pix0 = (blockIdx.x * BLK + t) * PPT;

    // ---- load x: 2 consecutive pixels x 8 ch = 64 B contiguous per lane ----
    float xr[PPT][IN];
    {
        const float4* xp = (const float4*)(x + (size_t)pix0 * IN);
        #pragma unroll
        for (int p = 0; p < PPT; ++p) {
            float4 a = xp[2 * p];
            float4 b = xp[2 * p + 1];
            xr[p][0] = a.x; xr[p][1] = a.y; xr[p][2] = a.z; xr[p][3] = a.w;
            xr[p][4] = b.x; xr[p][5] = b.y; xr[p][6] = b.z; xr[p][7] = b.w;
        }
    }

    // ---- layer 0: h0 = relu(x @ w0 + b0) ----
    float h0[PPT][HID];
    #pragma unroll
    for (int j = 0; j < HID; ++j) {
        const float4 wa = ((const float4*)sW0[j])[0];
        const float4 wb = ((const float4*)sW0[j])[1];
        const float bj = sB0[j];
        #pragma unroll
        for (int p = 0; p < PPT; ++p) {
            float acc = bj;
            acc = fmaf(xr[p][0], wa.x, acc);
            acc = fmaf(xr[p][1], wa.y, acc);
            acc = fmaf(xr[p][2], wa.z, acc);
            acc = fmaf(xr[p][3], wa.w, acc);
            acc = fmaf(xr[p][4], wb.x, acc);
            acc = fmaf(xr[p][5], wb.y, acc);
            acc = fmaf(xr[p][6], wb.z, acc);
            acc = fmaf(xr[p][7], wb.w, acc);
            h0[p][j] = fmaxf(acc, 0.0f);
        }
    }

    // ---- layer 1: h1 = relu(h0 @ w1 + b1) ----
    float h1[PPT][HID];
    #pragma unroll
    for (int j = 0; j < HID; ++j) {
        const float4 wa = ((const float4*)sW1[j])[0];
        const float4 wb = ((const float4*)sW1[j])[1];
        const float4 wc = ((const float4*)sW1[j])[2];
        const float4 wd = ((const float4*)sW1[j])[3];
        const float bj = sB1[j];
        #pragma unroll
        for (int p = 0; p < PPT; ++p) {
            float acc = bj;
            acc = fmaf(h0[p][0],  wa.x, acc);
            acc = fmaf(h0[p][1],  wa.y, acc);
            acc = fmaf(h0[p][2],  wa.z, acc);
            acc = fmaf(h0[p][3],  wa.w, acc);
            acc = fmaf(h0[p][4],  wb.x, acc);
            acc = fmaf(h0[p][5],  wb.y, acc);
            acc = fmaf(h0[p][6],  wb.z, acc);
            acc = fmaf(h0[p][7],  wb.w, acc);
            acc = fmaf(h0[p][8],  wc.x, acc);
            acc = fmaf(h0[p][9],  wc.y, acc);
            acc = fmaf(h0[p][10], wc.z, acc);
            acc = fmaf(h0[p][11], wc.w, acc);
            acc = fmaf(h0[p][12], wd.x, acc);
            acc = fmaf(h0[p][13], wd.y, acc);
            acc = fmaf(h0[p][14], wd.z, acc);
            acc = fmaf(h0[p][15], wd.w, acc);
            h1[p][j] = fmaxf(acc, 0.0f);
        }
    }

    // ---- mask load (uniform branch on detected layout) ----
    int mv[PPT];
    if (mflag) {
        uchar2 m2 = *(const uchar2*)((const unsigned char*)mask + pix0);
        mv[0] = m2.x; mv[1] = m2.y;
    } else {
        int2 m2 = *(const int2*)((const int*)mask + pix0);
        mv[0] = m2.x; mv[1] = m2.y;
    }

    // ---- layer 2 + sigmoid + blend, straight into LDS staging ----
    #pragma unroll
    for (int p = 0; p < PPT; ++p) {
        const float res = xr[p][3];
        float ov[OUTC];
        #pragma unroll
        for (int j = 0; j < OUTC; ++j) {
            const float4 wa = ((const float4*)sW2[j])[0];
            const float4 wb = ((const float4*)sW2[j])[1];
            const float4 wc = ((const float4*)sW2[j])[2];
            const float4 wd = ((const float4*)sW2[j])[3];
            float acc = sB2[j];
            acc = fmaf(h1[p][0],  wa.x, acc);
            acc = fmaf(h1[p][1],  wa.y, acc);
            acc = fmaf(h1[p][2],  wa.z, acc);
            acc = fmaf(h1[p][3],  wa.w, acc);
            acc = fmaf(h1[p][4],  wb.x, acc);
            acc = fmaf(h1[p][5],  wb.y, acc);
            acc = fmaf(h1[p][6],  wb.z, acc);
            acc = fmaf(h1[p][7],  wb.w, acc);
            acc = fmaf(h1[p][8],  wc.x, acc);
            acc = fmaf(h1[p][9],  wc.y, acc);
            acc = fmaf(h1[p][10], wc.z, acc);
            acc = fmaf(h1[p][11], wc.w, acc);
            acc = fmaf(h1[p][12], wd.x, acc);
            acc = fmaf(h1[p][13], wd.y, acc);
            acc = fmaf(h1[p][14], wd.z, acc);
            acc = fmaf(h1[p][15], wd.w, acc);
            float e = __expf(-acc);
            float y = __builtin_amdgcn_rcpf(1.0f + e);
            float rgb = xr[p][j];
            float bl = fmaf(res, y - rgb, rgb);      // (1-res)*rgb + res*y
            ov[j] = mv[p] ? bl : 0.0f;
        }
        // 12 B per pixel into LDS (float2 + float)
        float* sp = sOut + (size_t)(t * PPT + p) * OUTC;
        ((float2*)sp)[0] = make_float2(ov[0], ov[1]);
        sp[2] = ov[2];
    }
    __syncthreads();

    // ---- contiguous wave-level stores: 384 float4 = 6 KB per block ----
    {
        const float4* s4 = (const float4*)sOut;
        float4* o4 = (float4*)(out + (size_t)blockIdx.x * (BLK * PPT * OUTC));
        o4[t] = s4[t];
        if (t < (BLK * PPT * OUTC) / 4 - BLK) o4[BLK + t] = s4[BLK + t];
    }
}

extern "C" void kernel_launch(void* const* d_in, const int* in_sizes, int n_in,
                              void* d_out, int out_size, void* d_ws, size_t ws_size,
                              hipStream_t stream) {
    const float* x    = (const float*)d_in[0];
    const void*  mask = d_in[1];
    const float* w0   = (const float*)d_in[2];
    const float* b0   = (const float*)d_in[3];
    const float* w1   = (const float*)d_in[4];
    const float* b1   = (const float*)d_in[5];
    const float* w2   = (const float*)d_in[6];
    const float* b2   = (const float*)d_in[7];
    float* out = (float*)d_out;
    int* flag  = (int*)d_ws;

    detect_mask_kernel<<<1, 64, 0, stream>>>((const unsigned int*)mask, flag);

    const int grid = NPIX / (BLK * PPT);  // 16384
    colormlp_kernel<<<grid, BLK, 0, stream>>>(x, mask, w0, b0, w1, b1, w2, b2,
                                              out, flag);
}

// Round 3
// 1739.263 us; speedup vs baseline: 1.2812x; 1.2812x over previous
//
#include <hip/hip_runtime.h>

#define NPIX (8 * 1024 * 1024)
#define IN 8
#define HID 16
#define OUTC 3
#define BLK 256
#define PPT 2   // pixels per thread

// Mask may be stored as 1-byte bools (numpy bool_) or widened int32 — detect at
// runtime. Random 0/1 bytes packed into u32 words give values > 1 almost surely;
// int32 storage gives only {0,1}. Reads 2 KB, safe under both layouts (>= 8 MB).
__global__ void detect_mask_kernel(const unsigned int* __restrict__ m,
                                   int* __restrict__ flag) {
    const int t = threadIdx.x;            // 64 lanes, one wave
    unsigned int acc = 0u;
    #pragma unroll
    for (int k = 0; k < 8; ++k) acc |= m[t * 8 + k];
    const unsigned long long any_big = __ballot(acc > 1u);
    if (t == 0) *flag = (any_big != 0ull) ? 1 : 0;  // 1 => byte-mask
}

// (256,4) snapped the allocator to 64 VGPR -> 8.4 GB spill traffic (round 2).
// (256,3) caps at ~170 -> allocator lands on 128, live set ~100 fits, no spill.
__global__ void __launch_bounds__(BLK, 3) colormlp_kernel(
    const float* __restrict__ x,
    const void*  __restrict__ mask,
    const float* __restrict__ w0, const float* __restrict__ b0,
    const float* __restrict__ w1, const float* __restrict__ b1,
    const float* __restrict__ w2, const float* __restrict__ b2,
    float* __restrict__ out,
    const int* __restrict__ flag)
{
    // Weights transposed so each output-neuron row is contiguous -> ds_read_b128
    // broadcast (all lanes same address, conflict-free).
    __shared__ __align__(16) float sW0[HID][IN];
    __shared__ __align__(16) float sW1[HID][HID];
    __shared__ __align__(16) float sW2[OUTC][HID];
    __shared__ float sB0[HID];
    __shared__ float sB1[HID];
    __shared__ float sB2[OUTC];
    // Output staging: block covers 512 px * 3 ch = 1536 floats = 6 KB.
    __shared__ __align__(16) float sOut[BLK * PPT * OUTC];

    const int t = threadIdx.x;
    if (t < HID * IN)   { int j = t >> 3, i = t & 7;  sW0[j][i] = w0[i * HID + j]; }
    {                     int j = t >> 4, i = t & 15; sW1[j][i] = w1[i * HID + j]; }
    if (t < OUTC * HID) { int j = t >> 4, i = t & 15; sW2[j][i] = w2[i * OUTC + j]; }
    if (t < HID)  { sB0[t] = b0[t]; sB1[t] = b1[t]; }
    if (t < OUTC) { sB2[t] = b2[t]; }
    __syncthreads();

    const int mflag = *flag;

    const unsigned int pix0 = (blockIdx.x * BLK + t) * PPT;

    // ---- load x: 2 consecutive pixels x 8 ch = 64 B contiguous per lane ----
    float xr[PPT][IN];
    {
        const float4* xp = (const float4*)(x + (size_t)pix0 * IN);
        #pragma unroll
        for (int p = 0; p < PPT; ++p) {
            float4 a = xp[2 * p];
            float4 b = xp[2 * p + 1];
            xr[p][0] = a.x; xr[p][1] = a.y; xr[p][2] = a.z; xr[p][3] = a.w;
            xr[p][4] = b.x; xr[p][5] = b.y; xr[p][6] = b.z; xr[p][7] = b.w;
        }
    }

    // ---- layer 0: h0 = relu(x @ w0 + b0) ----
    float h0[PPT][HID];
    #pragma unroll
    for (int j = 0; j < HID; ++j) {
        const float4 wa = ((const float4*)sW0[j])[0];
        const float4 wb = ((const float4*)sW0[j])[1];
        const float bj = sB0[j];
        #pragma unroll
        for (int p = 0; p < PPT; ++p) {
            float acc = bj;
            acc = fmaf(xr[p][0], wa.x, acc);
            acc = fmaf(xr[p][1], wa.y, acc);
            acc = fmaf(xr[p][2], wa.z, acc);
            acc = fmaf(xr[p][3], wa.w, acc);
            acc = fmaf(xr[p][4], wb.x, acc);
            acc = fmaf(xr[p][5], wb.y, acc);
            acc = fmaf(xr[p][6], wb.z, acc);
            acc = fmaf(xr[p][7], wb.w, acc);
            h0[p][j] = fmaxf(acc, 0.0f);
        }
    }

    // ---- layer 1: h1 = relu(h0 @ w1 + b1) ----
    float h1[PPT][HID];
    #pragma unroll
    for (int j = 0; j < HID; ++j) {
        const float4 wa = ((const float4*)sW1[j])[0];
        const float4 wb = ((const float4*)sW1[j])[1];
        const float4 wc = ((const float4*)sW1[j])[2];
        const float4 wd = ((const float4*)sW1[j])[3];
        const float bj = sB1[j];
        #pragma unroll
        for (int p = 0; p < PPT; ++p) {
            float acc = bj;
            acc = fmaf(h0[p][0],  wa.x, acc);
            acc = fmaf(h0[p][1],  wa.y, acc);
            acc = fmaf(h0[p][2],  wa.z, acc);
            acc = fmaf(h0[p][3],  wa.w, acc);
            acc = fmaf(h0[p][4],  wb.x, acc);
            acc = fmaf(h0[p][5],  wb.y, acc);
            acc = fmaf(h0[p][6],  wb.z, acc);
            acc = fmaf(h0[p][7],  wb.w, acc);
            acc = fmaf(h0[p][8],  wc.x, acc);
            acc = fmaf(h0[p][9],  wc.y, acc);
            acc = fmaf(h0[p][10], wc.z, acc);
            acc = fmaf(h0[p][11], wc.w, acc);
            acc = fmaf(h0[p][12], wd.x, acc);
            acc = fmaf(h0[p][13], wd.y, acc);
            acc = fmaf(h0[p][14], wd.z, acc);
            acc = fmaf(h0[p][15], wd.w, acc);
            h1[p][j] = fmaxf(acc, 0.0f);
        }
    }

    // ---- mask load (uniform branch on detected layout) ----
    int mv[PPT];
    if (mflag) {
        uchar2 m2 = *(const uchar2*)((const unsigned char*)mask + pix0);
        mv[0] = m2.x; mv[1] = m2.y;
    } else {
        int2 m2 = *(const int2*)((const int*)mask + pix0);
        mv[0] = m2.x; mv[1] = m2.y;
    }

    // ---- layer 2 + sigmoid + blend, straight into LDS staging ----
    #pragma unroll
    for (int p = 0; p < PPT; ++p) {
        const float res = xr[p][3];
        float ov[OUTC];
        #pragma unroll
        for (int j = 0; j < OUTC; ++j) {
            const float4 wa = ((const float4*)sW2[j])[0];
            const float4 wb = ((const float4*)sW2[j])[1];
            const float4 wc = ((const float4*)sW2[j])[2];
            const float4 wd = ((const float4*)sW2[j])[3];
            float acc = sB2[j];
            acc = fmaf(h1[p][0],  wa.x, acc);
            acc = fmaf(h1[p][1],  wa.y, acc);
            acc = fmaf(h1[p][2],  wa.z, acc);
            acc = fmaf(h1[p][3],  wa.w, acc);
            acc = fmaf(h1[p][4],  wb.x, acc);
            acc = fmaf(h1[p][5],  wb.y, acc);
            acc = fmaf(h1[p][6],  wb.z, acc);
            acc = fmaf(h1[p][7],  wb.w, acc);
            acc = fmaf(h1[p][8],  wc.x, acc);
            acc = fmaf(h1[p][9],  wc.y, acc);
            acc = fmaf(h1[p][10], wc.z, acc);
            acc = fmaf(h1[p][11], wc.w, acc);
            acc = fmaf(h1[p][12], wd.x, acc);
            acc = fmaf(h1[p][13], wd.y, acc);
            acc = fmaf(h1[p][14], wd.z, acc);
            acc = fmaf(h1[p][15], wd.w, acc);
            float e = __expf(-acc);
            float y = __builtin_amdgcn_rcpf(1.0f + e);
            float rgb = xr[p][j];
            float bl = fmaf(res, y - rgb, rgb);      // (1-res)*rgb + res*y
            ov[j] = mv[p] ? bl : 0.0f;
        }
        // 12 B per pixel into LDS (float2 + float)
        float* sp = sOut + (size_t)(t * PPT + p) * OUTC;
        ((float2*)sp)[0] = make_float2(ov[0], ov[1]);
        sp[2] = ov[2];
    }
    __syncthreads();

    // ---- contiguous wave-level stores: 384 float4 = 6 KB per block ----
    {
        const float4* s4 = (const float4*)sOut;
        float4* o4 = (float4*)(out + (size_t)blockIdx.x * (BLK * PPT * OUTC));
        o4[t] = s4[t];
        if (t < (BLK * PPT * OUTC) / 4 - BLK) o4[BLK + t] = s4[BLK + t];
    }
}

extern "C" void kernel_launch(void* const* d_in, const int* in_sizes, int n_in,
                              void* d_out, int out_size, void* d_ws, size_t ws_size,
                              hipStream_t stream) {
    const float* x    = (const float*)d_in[0];
    const void*  mask = d_in[1];
    const float* w0   = (const float*)d_in[2];
    const float* b0   = (const float*)d_in[3];
    const float* w1   = (const float*)d_in[4];
    const float* b1   = (const float*)d_in[5];
    const float* w2   = (const float*)d_in[6];
    const float* b2   = (const float*)d_in[7];
    float* out = (float*)d_out;
    int* flag  = (int*)d_ws;

    detect_mask_kernel<<<1, 64, 0, stream>>>((const unsigned int*)mask, flag);

    const int grid = NPIX / (BLK * PPT);  // 16384
    colormlp_kernel<<<grid, BLK, 0, stream>>>(x, mask, w0, b0, w1, b1, w2, b2,
                                              out, flag);
}

// Round 4
// 499.450 us; speedup vs baseline: 4.4617x; 3.4824x over previous
//
#include <hip/hip_runtime.h>

#define NPIX (8 * 1024 * 1024)
#define IN 8
#define HID 16
#define OUTC 3
#define BLK 256
#define PPT 2   // pixels per thread

// d_ws float layout: [0]=mask-format flag (int), [16..143]=w0^T (16 rows x 8),
// [144..399]=w1^T (16 rows x 16), [400..447]=w2^T (3 rows x 16),
// [448..463]=b0, [464..479]=b1, [480..482]=b2.
#define WS_W0T 16
#define WS_W1T 144
#define WS_W2T 400
#define WS_B0  448
#define WS_B1  464
#define WS_B2  480

// Prep: detect mask storage format (1-byte bool vs int32) + transpose weights
// into d_ws so each output-neuron row is contiguous -> s_load_dwordx4/x8.
__global__ void prep_kernel(const unsigned int* __restrict__ m,
                            const float* __restrict__ w0, const float* __restrict__ b0,
                            const float* __restrict__ w1, const float* __restrict__ b1,
                            const float* __restrict__ w2, const float* __restrict__ b2,
                            float* __restrict__ ws) {
    const int t = threadIdx.x;  // 256
    if (t < 64) {  // wave 0: packed bytes of random 0/1 give u32 words > 1 a.s.
        unsigned int acc = 0u;
        #pragma unroll
        for (int k = 0; k < 8; ++k) acc |= m[t * 8 + k];
        const unsigned long long big = __ballot(acc > 1u);
        if (t == 0) ((int*)ws)[0] = big ? 1 : 0;   // 1 => byte-mask
    }
    if (t < HID * IN)  { int j = t >> 3, i = t & 7;   ws[WS_W0T + j * IN  + i] = w0[i * HID  + j]; }
    {                    int j = t >> 4, i = t & 15;  ws[WS_W1T + j * HID + i] = w1[i * HID  + j]; }
    if (t < OUTC * HID){ int j = t >> 4, i = t & 15;  ws[WS_W2T + j * HID + i] = w2[i * OUTC + j]; }
    if (t < HID)  { ws[WS_B0 + t] = b0[t]; ws[WS_B1 + t] = b1[t]; }
    if (t < OUTC) { ws[WS_B2 + t] = b2[t]; }
}

// Weights come in via uniform (scalar) loads -> SGPRs; VGPRs hold only pixel
// state (~90 live). No launch_bounds min-waves: caps made the allocator spill
// 7-8 GB to scratch in rounds 2-3.
__global__ void __launch_bounds__(BLK) colormlp_kernel(
    const float* __restrict__ x,
    const void*  __restrict__ mask,
    const float* __restrict__ ws,
    float* __restrict__ out)
{
    // Output staging only: 512 px * 3 ch = 6 KB.
    __shared__ __align__(16) float sOut[BLK * PPT * OUTC];

    const int t = threadIdx.x;
    const int mflag = ((const int*)ws)[0];

    const unsigned int pix0 = (blockIdx.x * BLK + t) * PPT;

    // ---- load x: 2 consecutive pixels x 8 ch = 64 B contiguous per lane ----
    // x0[p] = (r, g, b, res); x1[p] = channels 4..7.
    float4 x0[PPT], x1[PPT];
    {
        const float4* xp = (const float4*)(x + (size_t)pix0 * IN);
        #pragma unroll
        for (int p = 0; p < PPT; ++p) { x0[p] = xp[2 * p]; x1[p] = xp[2 * p + 1]; }
    }

    // ---- layer 0: h0 = relu(x @ w0 + b0), weights from SGPRs ----
    float h0[PPT][HID];
    #pragma unroll
    for (int j = 0; j < HID; ++j) {
        const float* wr = ws + WS_W0T + j * IN;   // uniform address
        float w[IN];
        #pragma unroll
        for (int i = 0; i < IN; ++i) w[i] = wr[i];
        const float bj = ws[WS_B0 + j];
        #pragma unroll
        for (int p = 0; p < PPT; ++p) {
            float acc = bj;
            acc = fmaf(x0[p].x, w[0], acc);
            acc = fmaf(x0[p].y, w[1], acc);
            acc = fmaf(x0[p].z, w[2], acc);
            acc = fmaf(x0[p].w, w[3], acc);
            acc = fmaf(x1[p].x, w[4], acc);
            acc = fmaf(x1[p].y, w[5], acc);
            acc = fmaf(x1[p].z, w[6], acc);
            acc = fmaf(x1[p].w, w[7], acc);
            h0[p][j] = fmaxf(acc, 0.0f);
        }
    }
    __builtin_amdgcn_sched_barrier(0);  // fence hoisting between layers

    // ---- layer 1: h1 = relu(h0 @ w1 + b1) ----
    float h1[PPT][HID];
    #pragma unroll
    for (int j = 0; j < HID; ++j) {
        const float* wr = ws + WS_W1T + j * HID;
        float w[HID];
        #pragma unroll
        for (int i = 0; i < HID; ++i) w[i] = wr[i];
        const float bj = ws[WS_B1 + j];
        #pragma unroll
        for (int p = 0; p < PPT; ++p) {
            float acc = bj;
            #pragma unroll
            for (int i = 0; i < HID; ++i) acc = fmaf(h0[p][i], w[i], acc);
            h1[p][j] = fmaxf(acc, 0.0f);
        }
    }
    __builtin_amdgcn_sched_barrier(0);

    // ---- mask load (uniform branch on detected layout) ----
    int mv[PPT];
    if (mflag) {
        uchar2 m2 = *(const uchar2*)((const unsigned char*)mask + pix0);
        mv[0] = m2.x; mv[1] = m2.y;
    } else {
        int2 m2 = *(const int2*)((const int*)mask + pix0);
        mv[0] = m2.x; mv[1] = m2.y;
    }

    // ---- layer 2 + sigmoid + blend -> LDS staging ----
    #pragma unroll
    for (int p = 0; p < PPT; ++p) {
        const float res = x0[p].w;
        float ov[OUTC];
        #pragma unroll
        for (int j = 0; j < OUTC; ++j) {
            const float* wr = ws + WS_W2T + j * HID;
            float acc = ws[WS_B2 + j];
            #pragma unroll
            for (int i = 0; i < HID; ++i) acc = fmaf(h1[p][i], wr[i], acc);
            float e = __expf(-acc);
            float y = __builtin_amdgcn_rcpf(1.0f + e);
            float rgb = (j == 0) ? x0[p].x : (j == 1) ? x0[p].y : x0[p].z;
            float bl = fmaf(res, y - rgb, rgb);      // (1-res)*rgb + res*y
            ov[j] = mv[p] ? bl : 0.0f;
        }
        float* sp = sOut + (size_t)(t * PPT + p) * OUTC;
        ((float2*)sp)[0] = make_float2(ov[0], ov[1]);
        sp[2] = ov[2];
    }
    __syncthreads();

    // ---- contiguous wave-level stores: 384 float4 = 6 KB per block ----
    {
        const float4* s4 = (const float4*)sOut;
        float4* o4 = (float4*)(out + (size_t)blockIdx.x * (BLK * PPT * OUTC));
        o4[t] = s4[t];
        if (t < (BLK * PPT * OUTC) / 4 - BLK) o4[BLK + t] = s4[BLK + t];
    }
}

extern "C" void kernel_launch(void* const* d_in, const int* in_sizes, int n_in,
                              void* d_out, int out_size, void* d_ws, size_t ws_size,
                              hipStream_t stream) {
    const float* x    = (const float*)d_in[0];
    const void*  mask = d_in[1];
    const float* w0   = (const float*)d_in[2];
    const float* b0   = (const float*)d_in[3];
    const float* w1   = (const float*)d_in[4];
    const float* b1   = (const float*)d_in[5];
    const float* w2   = (const float*)d_in[6];
    const float* b2   = (const float*)d_in[7];
    float* out = (float*)d_out;
    float* ws  = (float*)d_ws;

    prep_kernel<<<1, BLK, 0, stream>>>((const unsigned int*)mask,
                                       w0, b0, w1, b1, w2, b2, ws);

    const int grid = NPIX / (BLK * PPT);  // 16384
    colormlp_kernel<<<grid, BLK, 0, stream>>>(x, mask, ws, out);
}